// Round 7
// baseline (914.080 us; speedup 1.0000x reference)
//
#include <hip/hip_runtime.h>

#define NN    60000
#define NODES 100000
#define DD    64
#define NNZ   3200000
#define BB    1024
#define NEG   0.2f
#define RPB   196                        // rows per bucket
#define NBUCK 511                        // ceil(NODES/RPB)
#define EPB   8192                       // edges per sort block
#define NPB   ((NNZ + EPB - 1) / EPB)    // 391
#define CAP   7000                       // bucket capacity (mean 6272, sd~79)
#define BCAP  7168                       // LDS edge capacity in k_csr
#define NSEG  13                         // column segments (col>>13)
#define KEYN  (NSEG * RPB)               // 2548 sort keys per bucket
#define SPB   (KEYN + 1)                 // starts entries per bucket

// ---------------------------------------------------------------- init x = concat(eu, ei); also init gcur
__global__ __launch_bounds__(256) void k_init_x(const float* __restrict__ eu,
                                                const float* __restrict__ ei,
                                                float* __restrict__ x,
                                                int* __restrict__ gcur) {
    int i = blockIdx.x * 256 + threadIdx.x;          // float4 index
    if (i < NBUCK) gcur[i] = i * CAP;
    const int TOT = NODES * DD / 4;
    if (i >= TOT) return;
    const int UE = NN * DD / 4;
    float4 v = (i < UE) ? ((const float4*)eu)[i] : ((const float4*)ei)[i - UE];
    ((float4*)x)[i] = v;
}

// ---------------------------------------------------------------- bucket sort -> bulk
__global__ __launch_bounds__(512) void k_place(const int* __restrict__ row,
                                               const int* __restrict__ col,
                                               const float* __restrict__ val,
                                               int* __restrict__ gcur,
                                               int2* __restrict__ bulk) {
    __shared__ int rows_l[EPB];                // 32 KB
    __shared__ unsigned short perm[EPB];       // 16 KB
    __shared__ int h[NBUCK], bloc[NBUCK], bcur[NBUCK], gseg[NBUCK];
    __shared__ int sc[512];
    int t = threadIdx.x;
    if (t < NBUCK) h[t] = 0;
    __syncthreads();
    int base = blockIdx.x * EPB;
    int n = min(EPB, NNZ - base);
    for (int k = t; k < n; k += 512) {
        int r = row[base + k];
        rows_l[k] = r;
        atomicAdd(&h[r / RPB], 1);
    }
    __syncthreads();
    {
        int v = (t < NBUCK) ? h[t] : 0;
        sc[t] = v;
        __syncthreads();
        for (int off = 1; off < 512; off <<= 1) {
            int u = (t >= off) ? sc[t - off] : 0;
            __syncthreads();
            sc[t] += u;
            __syncthreads();
        }
        if (t < NBUCK) {
            int ex = sc[t] - v;
            bloc[t] = ex;
            bcur[t] = ex;
            gseg[t] = v ? atomicAdd(&gcur[t], v) : 0;
        }
    }
    __syncthreads();
    for (int k = t; k < n; k += 512) {
        int p = atomicAdd(&bcur[rows_l[k] / RPB], 1);
        perm[p] = (unsigned short)k;
    }
    __syncthreads();
    for (int j = t; j < n; j += 512) {
        int k = perm[j];
        int r = rows_l[k];
        int b = r / RPB;
        int addr = gseg[b] + (j - bloc[b]);
        bulk[addr] = make_int2(((r - b * RPB) << 17) | col[base + k],
                               __float_as_int(val[base + k]));
    }
}

// ---------------------------------------------------------------- per-bucket (colseg,row) sort
// in-place; emit per-key span starts (bucket-cumulative + sentinel)
__global__ __launch_bounds__(512) void k_csr(const int* __restrict__ gcur,
                                             int2* __restrict__ bulk,
                                             int* __restrict__ starts) {
    __shared__ int2 eds[BCAP];                 // 56 KB
    __shared__ int cnt[KEYN], pos[KEYN];       // 20 KB
    __shared__ int part[512];
    int b = blockIdx.x, t = threadIdx.x;
    int lo = b * CAP;
    int n = gcur[b] - lo;
    for (int k = t; k < KEYN; k += 512) cnt[k] = 0;
    __syncthreads();
    for (int i = t; i < n; i += 512) {
        int2 ed = bulk[lo + i];
        eds[i] = ed;
        int lr = ed.x >> 17, c = ed.x & 0x1FFFF;
        atomicAdd(&cnt[(c >> 13) * RPB + lr], 1);
    }
    __syncthreads();
    // two-level exclusive scan over KEYN bins (5 bins/thread)
    int run = 0;
#pragma unroll
    for (int j = 0; j < 5; ++j) {
        int k = t * 5 + j;
        if (k < KEYN) { pos[k] = run; run += cnt[k]; }
    }
    part[t] = run;
    __syncthreads();
    for (int off = 1; off < 512; off <<= 1) {
        int u = (t >= off) ? part[t - off] : 0;
        __syncthreads();
        part[t] += u;
        __syncthreads();
    }
    int poff = part[t] - run;
#pragma unroll
    for (int j = 0; j < 5; ++j) {
        int k = t * 5 + j;
        if (k < KEYN) pos[k] += poff;
    }
    __syncthreads();
    for (int k = t; k < KEYN; k += 512) {
        starts[b * SPB + k] = lo + pos[k];
        cnt[k] = pos[k];                      // reuse as cursor
    }
    if (t == 0) starts[b * SPB + KEYN] = lo + n;
    __syncthreads();
    for (int i = t; i < n; i += 512) {
        int2 ed = eds[i];
        int lr = ed.x >> 17, c = ed.x & 0x1FFFF;
        int p = atomicAdd(&cnt[(c >> 13) * RPB + lr], 1);
        bulk[lo + p] = make_int2(c, ed.y);
    }
}

// ---------------------------------------------------------------- convoyed seg-major pull SpMM
// 1 block/bucket (all 511 co-resident, 2/CU), LDS fp32 acc, per-wave row ownership.
// All blocks sweep colsegs together -> active x slice (~2 MB) stays L2-resident.
__global__ __launch_bounds__(1024) void k_cspmm(const int* __restrict__ starts,
                                                const int2* __restrict__ cv,
                                                const float* __restrict__ x,
                                                float* __restrict__ lie) {
    __shared__ float acc[RPB * DD];            // 49 KB
    int t = threadIdx.x, b = blockIdx.x;
    float4* av = (float4*)acc;
    for (int i = t; i < RPB * 16; i += 1024) av[i] = make_float4(0.f, 0.f, 0.f, 0.f);
    __syncthreads();
    int wid = t >> 6, lane = t & 63;
    int sb = b * SPB;
    for (int seg = 0; seg < NSEG; ++seg) {
        for (int r = wid; r < RPB; r += 16) {
            int key = sb + seg * RPB + r;
            int s = starts[key], e = starts[key + 1];
            if (s == e) continue;
            float f = 0.f;
            int g = s;
            for (; g + 2 <= e; g += 2) {
                int2 e0 = cv[g], e1 = cv[g + 1];
                float x0 = x[e0.x * DD + lane];
                float x1 = x[e1.x * DD + lane];
                f = fmaf(__int_as_float(e0.y), x0, f);
                f = fmaf(__int_as_float(e1.y), x1, f);
            }
            if (g < e) {
                int2 e0 = cv[g];
                f = fmaf(__int_as_float(e0.y), x[e0.x * DD + lane], f);
            }
            acc[r * DD + lane] += f;
        }
        // no barrier: each wave exclusively owns its rows
    }
    __syncthreads();
    int row0 = b * RPB;
    for (int i = t; i < RPB * 16; i += 1024) {
        int gr = row0 + (i >> 4);
        if (gr < NODES) ((float4*)lie)[gr * 16 + (i & 15)] = av[i];
    }
}

// ---------------------------------------------------------------- fused layer GEMM
__global__ __launch_bounds__(256) void k_gemm(float* __restrict__ x,
                                              const float* __restrict__ lie,
                                              const float* __restrict__ W1,
                                              const float* __restrict__ W2,
                                              const float* __restrict__ b1,
                                              const float* __restrict__ b2) {
    __shared__ float A1[64 * 64];
    __shared__ float A2[64 * 64];
    __shared__ float Ws1[64 * 64];
    __shared__ float Ws2[64 * 64];

    const int t = threadIdx.x;
    const int row0 = blockIdx.x * 64;

    {
        const float4* w1v = (const float4*)W1;
        const float4* w2v = (const float4*)W2;
        float4* s1v = (float4*)Ws1;
        float4* s2v = (float4*)Ws2;
#pragma unroll
        for (int q = 0; q < 4; ++q) {
            s1v[q * 256 + t] = w1v[q * 256 + t];
            s2v[q * 256 + t] = w2v[q * 256 + t];
        }
    }
#pragma unroll
    for (int q = 0; q < 4; ++q) {
        int f4 = q * 256 + t;
        int rl = f4 >> 4;
        int c4 = f4 & 15;
        int gr = row0 + rl;
        float4 lv = make_float4(0.f, 0.f, 0.f, 0.f);
        float4 xv = make_float4(0.f, 0.f, 0.f, 0.f);
        if (gr < NODES) {
            lv = *(const float4*)&lie[gr * DD + c4 * 4];
            xv = *(const float4*)&x[gr * DD + c4 * 4];
        }
        int sg = c4 ^ (rl & 15);
        ((float4*)A1)[rl * 16 + sg] = lv;
        ((float4*)A2)[rl * 16 + sg] = make_float4(lv.x * xv.x, lv.y * xv.y,
                                                  lv.z * xv.z, lv.w * xv.w);
    }
    __syncthreads();

    const int tx = t & 15;
    const int ty = t >> 4;
    float bs[4];
    {
        float4 bb1 = *(const float4*)&b1[tx * 4];
        float4 bb2 = *(const float4*)&b2[tx * 4];
        bs[0] = bb1.x + bb2.x; bs[1] = bb1.y + bb2.y;
        bs[2] = bb1.z + bb2.z; bs[3] = bb1.w + bb2.w;
    }
    float acc[4][4];
#pragma unroll
    for (int i = 0; i < 4; ++i)
#pragma unroll
        for (int j = 0; j < 4; ++j) acc[i][j] = bs[j];

    for (int k4 = 0; k4 < 16; ++k4) {
        float4 a1[4], a2[4];
#pragma unroll
        for (int i = 0; i < 4; ++i) {
            int r = ty * 4 + i;
            int sg = k4 ^ (r & 15);
            a1[i] = ((const float4*)A1)[r * 16 + sg];
            a2[i] = ((const float4*)A2)[r * 16 + sg];
        }
#pragma unroll
        for (int kk = 0; kk < 4; ++kk) {
            float4 w1 = ((const float4*)Ws1)[(k4 * 4 + kk) * 16 + tx];
            float4 w2 = ((const float4*)Ws2)[(k4 * 4 + kk) * 16 + tx];
#pragma unroll
            for (int i = 0; i < 4; ++i) {
                float av1 = (&a1[i].x)[kk];
                float av2 = (&a2[i].x)[kk];
                acc[i][0] = fmaf(av1, w1.x, fmaf(av2, w2.x, acc[i][0]));
                acc[i][1] = fmaf(av1, w1.y, fmaf(av2, w2.y, acc[i][1]));
                acc[i][2] = fmaf(av1, w1.z, fmaf(av2, w2.z, acc[i][2]));
                acc[i][3] = fmaf(av1, w1.w, fmaf(av2, w2.w, acc[i][3]));
            }
        }
    }
#pragma unroll
    for (int i = 0; i < 4; ++i) {
        int gr = row0 + ty * 4 + i;
        if (gr < NODES) {
            float4 o;
            o.x = acc[i][0] >= 0.f ? acc[i][0] : NEG * acc[i][0];
            o.y = acc[i][1] >= 0.f ? acc[i][1] : NEG * acc[i][1];
            o.z = acc[i][2] >= 0.f ? acc[i][2] : NEG * acc[i][2];
            o.w = acc[i][3] >= 0.f ? acc[i][3] : NEG * acc[i][3];
            *(float4*)&x[gr * DD + tx * 4] = o;
        }
    }
}

// ---------------------------------------------------------------- gather layer repr into output
__global__ __launch_bounds__(256) void k_gather(const float* __restrict__ x,
                                                const int* __restrict__ su,
                                                const int* __restrict__ oi,
                                                const int* __restrict__ ui,
                                                float* __restrict__ out, int layer) {
    int w    = (blockIdx.x * 256 + threadIdx.x) >> 6;
    int lane = threadIdx.x & 63;
    if (w >= 3 * BB) return;
    int g = w >> 10, b = w & 1023;
    int node = (g == 0) ? su[b] : (NN + ((g == 1) ? oi[b] : ui[b]));
    out[w * 256 + layer * 64 + lane] = x[node * DD + lane];
}

// ---------------------------------------------------------------- launch
extern "C" void kernel_launch(void* const* d_in, const int* in_sizes, int n_in,
                              void* d_out, int out_size, void* d_ws, size_t ws_size,
                              hipStream_t stream) {
    const int*   edge_row = (const int*)d_in[0];
    const int*   edge_col = (const int*)d_in[1];
    const float* edge_val = (const float*)d_in[2];
    const float* eu = (const float*)d_in[3];
    const float* ei = (const float*)d_in[4];
    const float* W1 = (const float*)d_in[5];
    const float* W2 = (const float*)d_in[6];
    const float* b1 = (const float*)d_in[7];
    const float* b2 = (const float*)d_in[8];
    const int*   su = (const int*)d_in[9];
    const int*   oi = (const int*)d_in[10];
    const int*   ui = (const int*)d_in[11];
    float* out = (float*)d_out;

    // workspace carve (~85 MB)
    float* x      = (float*)d_ws;                    // 25.6 MB
    float* lie    = x + NODES * DD;                  // 25.6 MB
    int2*  bulk   = (int2*)(lie + NODES * DD);       // NBUCK*CAP int2 (28.6 MB)
    int*   gcur   = (int*)(bulk + NBUCK * CAP);      // NBUCK
    int*   starts = gcur + NBUCK + 1;                // NBUCK*SPB (5.2 MB)

    k_init_x<<<(NODES * DD / 4 + 255) / 256, 256, 0, stream>>>(eu, ei, x, gcur);
    k_gather<<<(3 * BB * 64 + 255) / 256, 256, 0, stream>>>(x, su, oi, ui, out, 0);

    k_place<<<NPB, 512, 0, stream>>>(edge_row, edge_col, edge_val, gcur, bulk);
    k_csr<<<NBUCK, 512, 0, stream>>>(gcur, bulk, starts);

    for (int l = 0; l < 3; ++l) {
        k_cspmm<<<NBUCK, 1024, 0, stream>>>(starts, bulk, x, lie);
        k_gemm<<<(NODES + 63) / 64, 256, 0, stream>>>(x, lie,
                                                      W1 + l * 4096, W2 + l * 4096,
                                                      b1 + l * 64,  b2 + l * 64);
        k_gather<<<(3 * BB * 64 + 255) / 256, 256, 0, stream>>>(x, su, oi, ui, out, l + 1);
    }
}

// Round 8
// 590.453 us; speedup vs baseline: 1.5481x; 1.5481x over previous
//
#include <hip/hip_runtime.h>

#define NN    60000
#define NODES 100000
#define DD    64
#define NNZ   3200000
#define BB    1024
#define NEG   0.2f
#define RPB   196                        // rows per bucket
#define NBUCK 511                        // ceil(NODES/RPB)
#define EPB   8192                       // edges per sort block
#define NPB   ((NNZ + EPB - 1) / EPB)    // 391
#define CAP   7000                       // bucket capacity (mean 6272, sd~79)
#define BCAP  7168                       // LDS edge capacity in k_csr
#define NSEG  13                         // column segments (col>>13), ~2 MB x-slice each
#define KEYN  (NSEG * RPB)               // 2548 sort keys per bucket
#define SPB   (KEYN + 1)                 // starts entries per bucket

// ---------------------------------------------------------------- init x = concat(eu, ei); also init gcur
__global__ __launch_bounds__(256) void k_init_x(const float* __restrict__ eu,
                                                const float* __restrict__ ei,
                                                float* __restrict__ x,
                                                int* __restrict__ gcur) {
    int i = blockIdx.x * 256 + threadIdx.x;          // float4 index
    if (i < NBUCK) gcur[i] = i * CAP;
    const int TOT = NODES * DD / 4;
    if (i >= TOT) return;
    const int UE = NN * DD / 4;
    float4 v = (i < UE) ? ((const float4*)eu)[i] : ((const float4*)ei)[i - UE];
    ((float4*)x)[i] = v;
}

// ---------------------------------------------------------------- bucket sort -> bulk
__global__ __launch_bounds__(512) void k_place(const int* __restrict__ row,
                                               const int* __restrict__ col,
                                               const float* __restrict__ val,
                                               int* __restrict__ gcur,
                                               int2* __restrict__ bulk) {
    __shared__ int rows_l[EPB];                // 32 KB
    __shared__ unsigned short perm[EPB];       // 16 KB
    __shared__ int h[NBUCK], bloc[NBUCK], bcur[NBUCK], gseg[NBUCK];
    __shared__ int sc[512];
    int t = threadIdx.x;
    if (t < NBUCK) h[t] = 0;
    __syncthreads();
    int base = blockIdx.x * EPB;
    int n = min(EPB, NNZ - base);
    for (int k = t; k < n; k += 512) {
        int r = row[base + k];
        rows_l[k] = r;
        atomicAdd(&h[r / RPB], 1);
    }
    __syncthreads();
    {
        int v = (t < NBUCK) ? h[t] : 0;
        sc[t] = v;
        __syncthreads();
        for (int off = 1; off < 512; off <<= 1) {
            int u = (t >= off) ? sc[t - off] : 0;
            __syncthreads();
            sc[t] += u;
            __syncthreads();
        }
        if (t < NBUCK) {
            int ex = sc[t] - v;
            bloc[t] = ex;
            bcur[t] = ex;
            gseg[t] = v ? atomicAdd(&gcur[t], v) : 0;
        }
    }
    __syncthreads();
    for (int k = t; k < n; k += 512) {
        int p = atomicAdd(&bcur[rows_l[k] / RPB], 1);
        perm[p] = (unsigned short)k;
    }
    __syncthreads();
    for (int j = t; j < n; j += 512) {
        int k = perm[j];
        int r = rows_l[k];
        int b = r / RPB;
        int addr = gseg[b] + (j - bloc[b]);
        bulk[addr] = make_int2(((r - b * RPB) << 17) | col[base + k],
                               __float_as_int(val[base + k]));
    }
}

// ---------------------------------------------------------------- per-bucket (colseg,row) sort
// in-place (keeps packed local-row bits); emit per-key span starts + sentinel
__global__ __launch_bounds__(512) void k_csr(const int* __restrict__ gcur,
                                             int2* __restrict__ bulk,
                                             int* __restrict__ starts) {
    __shared__ int2 eds[BCAP];                 // 56 KB
    __shared__ int cnt[KEYN], pos[KEYN];       // 20 KB
    __shared__ int part[512];
    int b = blockIdx.x, t = threadIdx.x;
    int lo = b * CAP;
    int n = gcur[b] - lo;
    for (int k = t; k < KEYN; k += 512) cnt[k] = 0;
    __syncthreads();
    for (int i = t; i < n; i += 512) {
        int2 ed = bulk[lo + i];
        eds[i] = ed;
        int lr = ed.x >> 17, c = ed.x & 0x1FFFF;
        atomicAdd(&cnt[(c >> 13) * RPB + lr], 1);
    }
    __syncthreads();
    // two-level exclusive scan over KEYN bins (5 bins/thread)
    int run = 0;
#pragma unroll
    for (int j = 0; j < 5; ++j) {
        int k = t * 5 + j;
        if (k < KEYN) { pos[k] = run; run += cnt[k]; }
    }
    part[t] = run;
    __syncthreads();
    for (int off = 1; off < 512; off <<= 1) {
        int u = (t >= off) ? part[t - off] : 0;
        __syncthreads();
        part[t] += u;
        __syncthreads();
    }
    int poff = part[t] - run;
#pragma unroll
    for (int j = 0; j < 5; ++j) {
        int k = t * 5 + j;
        if (k < KEYN) pos[k] += poff;
    }
    __syncthreads();
    for (int k = t; k < KEYN; k += 512) {
        starts[b * SPB + k] = lo + pos[k];
        cnt[k] = pos[k];                      // reuse as cursor
    }
    if (t == 0) starts[b * SPB + KEYN] = lo + n;
    __syncthreads();
    for (int i = t; i < n; i += 512) {
        int2 ed = eds[i];
        int lr = ed.x >> 17, c = ed.x & 0x1FFFF;
        int p = atomicAdd(&cnt[(c >> 13) * RPB + lr], 1);
        bulk[lo + p] = ed;                    // keep packed (lr<<17 | col)
    }
}

// ---------------------------------------------------------------- convoyed seg-major pull SpMM
// 1 block/bucket (all 511 co-resident, 2/CU). Wave owns contiguous rows [r0,r1);
// per segment those edges are ONE contiguous run -> stream with 8 gathers in flight.
// Register accumulator flushed to LDS on (wave-uniform) row change. No LDS atomics.
__global__ __launch_bounds__(1024) void k_cspmm(const int* __restrict__ starts,
                                                const int2* __restrict__ cv,
                                                const float* __restrict__ x,
                                                float* __restrict__ lie) {
    __shared__ float acc[RPB * DD];            // 49 KB
    int t = threadIdx.x, b = blockIdx.x;
    float4* av = (float4*)acc;
    for (int i = t; i < RPB * 16; i += 1024) av[i] = make_float4(0.f, 0.f, 0.f, 0.f);
    __syncthreads();
    int wid = t >> 6, lane = t & 63;
    int r0 = (wid * RPB) >> 4;
    int r1 = ((wid + 1) * RPB) >> 4;
    int sb = b * SPB;
    for (int seg = 0; seg < NSEG; ++seg) {
        int s = starts[sb + seg * RPB + r0];
        int e = starts[sb + seg * RPB + r1];   // r1==RPB -> next seg's r0 / sentinel
        int cur = -1;
        float f = 0.f;
        int g = s;
        for (; g + 8 <= e; g += 8) {
            int2 ee[8];
#pragma unroll
            for (int j = 0; j < 8; ++j) ee[j] = cv[g + j];
            float xv[8];
#pragma unroll
            for (int j = 0; j < 8; ++j) xv[j] = x[(ee[j].x & 0x1FFFF) * DD + lane];
#pragma unroll
            for (int j = 0; j < 8; ++j) {
                int r = ee[j].x >> 17;
                if (r != cur) {                 // wave-uniform branch
                    if (cur >= 0) acc[cur * DD + lane] += f;
                    cur = r; f = 0.f;
                }
                f = fmaf(__int_as_float(ee[j].y), xv[j], f);
            }
        }
        for (; g < e; ++g) {
            int2 ed = cv[g];
            float xg = x[(ed.x & 0x1FFFF) * DD + lane];
            int r = ed.x >> 17;
            if (r != cur) {
                if (cur >= 0) acc[cur * DD + lane] += f;
                cur = r; f = 0.f;
            }
            f = fmaf(__int_as_float(ed.y), xg, f);
        }
        if (cur >= 0) acc[cur * DD + lane] += f;
    }
    __syncthreads();
    int row0 = b * RPB;
    for (int i = t; i < RPB * 16; i += 1024) {
        int gr = row0 + (i >> 4);
        if (gr < NODES) ((float4*)lie)[gr * 16 + (i & 15)] = av[i];
    }
}

// ---------------------------------------------------------------- fused layer GEMM
__global__ __launch_bounds__(256) void k_gemm(float* __restrict__ x,
                                              const float* __restrict__ lie,
                                              const float* __restrict__ W1,
                                              const float* __restrict__ W2,
                                              const float* __restrict__ b1,
                                              const float* __restrict__ b2) {
    __shared__ float A1[64 * 64];
    __shared__ float A2[64 * 64];
    __shared__ float Ws1[64 * 64];
    __shared__ float Ws2[64 * 64];

    const int t = threadIdx.x;
    const int row0 = blockIdx.x * 64;

    {
        const float4* w1v = (const float4*)W1;
        const float4* w2v = (const float4*)W2;
        float4* s1v = (float4*)Ws1;
        float4* s2v = (float4*)Ws2;
#pragma unroll
        for (int q = 0; q < 4; ++q) {
            s1v[q * 256 + t] = w1v[q * 256 + t];
            s2v[q * 256 + t] = w2v[q * 256 + t];
        }
    }
#pragma unroll
    for (int q = 0; q < 4; ++q) {
        int f4 = q * 256 + t;
        int rl = f4 >> 4;
        int c4 = f4 & 15;
        int gr = row0 + rl;
        float4 lv = make_float4(0.f, 0.f, 0.f, 0.f);
        float4 xv = make_float4(0.f, 0.f, 0.f, 0.f);
        if (gr < NODES) {
            lv = *(const float4*)&lie[gr * DD + c4 * 4];
            xv = *(const float4*)&x[gr * DD + c4 * 4];
        }
        int sg = c4 ^ (rl & 15);
        ((float4*)A1)[rl * 16 + sg] = lv;
        ((float4*)A2)[rl * 16 + sg] = make_float4(lv.x * xv.x, lv.y * xv.y,
                                                  lv.z * xv.z, lv.w * xv.w);
    }
    __syncthreads();

    const int tx = t & 15;
    const int ty = t >> 4;
    float bs[4];
    {
        float4 bb1 = *(const float4*)&b1[tx * 4];
        float4 bb2 = *(const float4*)&b2[tx * 4];
        bs[0] = bb1.x + bb2.x; bs[1] = bb1.y + bb2.y;
        bs[2] = bb1.z + bb2.z; bs[3] = bb1.w + bb2.w;
    }
    float acc[4][4];
#pragma unroll
    for (int i = 0; i < 4; ++i)
#pragma unroll
        for (int j = 0; j < 4; ++j) acc[i][j] = bs[j];

    for (int k4 = 0; k4 < 16; ++k4) {
        float4 a1[4], a2[4];
#pragma unroll
        for (int i = 0; i < 4; ++i) {
            int r = ty * 4 + i;
            int sg = k4 ^ (r & 15);
            a1[i] = ((const float4*)A1)[r * 16 + sg];
            a2[i] = ((const float4*)A2)[r * 16 + sg];
        }
#pragma unroll
        for (int kk = 0; kk < 4; ++kk) {
            float4 w1 = ((const float4*)Ws1)[(k4 * 4 + kk) * 16 + tx];
            float4 w2 = ((const float4*)Ws2)[(k4 * 4 + kk) * 16 + tx];
#pragma unroll
            for (int i = 0; i < 4; ++i) {
                float av1 = (&a1[i].x)[kk];
                float av2 = (&a2[i].x)[kk];
                acc[i][0] = fmaf(av1, w1.x, fmaf(av2, w2.x, acc[i][0]));
                acc[i][1] = fmaf(av1, w1.y, fmaf(av2, w2.y, acc[i][1]));
                acc[i][2] = fmaf(av1, w1.z, fmaf(av2, w2.z, acc[i][2]));
                acc[i][3] = fmaf(av1, w1.w, fmaf(av2, w2.w, acc[i][3]));
            }
        }
    }
#pragma unroll
    for (int i = 0; i < 4; ++i) {
        int gr = row0 + ty * 4 + i;
        if (gr < NODES) {
            float4 o;
            o.x = acc[i][0] >= 0.f ? acc[i][0] : NEG * acc[i][0];
            o.y = acc[i][1] >= 0.f ? acc[i][1] : NEG * acc[i][1];
            o.z = acc[i][2] >= 0.f ? acc[i][2] : NEG * acc[i][2];
            o.w = acc[i][3] >= 0.f ? acc[i][3] : NEG * acc[i][3];
            *(float4*)&x[gr * DD + tx * 4] = o;
        }
    }
}

// ---------------------------------------------------------------- gather layer repr into output
__global__ __launch_bounds__(256) void k_gather(const float* __restrict__ x,
                                                const int* __restrict__ su,
                                                const int* __restrict__ oi,
                                                const int* __restrict__ ui,
                                                float* __restrict__ out, int layer) {
    int w    = (blockIdx.x * 256 + threadIdx.x) >> 6;
    int lane = threadIdx.x & 63;
    if (w >= 3 * BB) return;
    int g = w >> 10, b = w & 1023;
    int node = (g == 0) ? su[b] : (NN + ((g == 1) ? oi[b] : ui[b]));
    out[w * 256 + layer * 64 + lane] = x[node * DD + lane];
}

// ---------------------------------------------------------------- launch
extern "C" void kernel_launch(void* const* d_in, const int* in_sizes, int n_in,
                              void* d_out, int out_size, void* d_ws, size_t ws_size,
                              hipStream_t stream) {
    const int*   edge_row = (const int*)d_in[0];
    const int*   edge_col = (const int*)d_in[1];
    const float* edge_val = (const float*)d_in[2];
    const float* eu = (const float*)d_in[3];
    const float* ei = (const float*)d_in[4];
    const float* W1 = (const float*)d_in[5];
    const float* W2 = (const float*)d_in[6];
    const float* b1 = (const float*)d_in[7];
    const float* b2 = (const float*)d_in[8];
    const int*   su = (const int*)d_in[9];
    const int*   oi = (const int*)d_in[10];
    const int*   ui = (const int*)d_in[11];
    float* out = (float*)d_out;

    // workspace carve (~85 MB)
    float* x      = (float*)d_ws;                    // 25.6 MB
    float* lie    = x + NODES * DD;                  // 25.6 MB
    int2*  bulk   = (int2*)(lie + NODES * DD);       // NBUCK*CAP int2 (28.6 MB)
    int*   gcur   = (int*)(bulk + NBUCK * CAP);      // NBUCK
    int*   starts = gcur + NBUCK + 1;                // NBUCK*SPB (5.2 MB)

    k_init_x<<<(NODES * DD / 4 + 255) / 256, 256, 0, stream>>>(eu, ei, x, gcur);
    k_gather<<<(3 * BB * 64 + 255) / 256, 256, 0, stream>>>(x, su, oi, ui, out, 0);

    k_place<<<NPB, 512, 0, stream>>>(edge_row, edge_col, edge_val, gcur, bulk);
    k_csr<<<NBUCK, 512, 0, stream>>>(gcur, bulk, starts);

    for (int l = 0; l < 3; ++l) {
        k_cspmm<<<NBUCK, 1024, 0, stream>>>(starts, bulk, x, lie);
        k_gemm<<<(NODES + 63) / 64, 256, 0, stream>>>(x, lie,
                                                      W1 + l * 4096, W2 + l * 4096,
                                                      b1 + l * 64,  b2 + l * 64);
        k_gather<<<(3 * BB * 64 + 255) / 256, 256, 0, stream>>>(x, su, oi, ui, out, l + 1);
    }
}